// Round 5
// baseline (194.147 us; speedup 1.0000x reference)
//
#include <hip/hip_runtime.h>

#define T_DIM 8192
#define NTH 512
#define NWAVE 8
#define GROUPS 4
#define NBIN 2048
#define KEEP_K 2867                 // max(1, round(8192 * 0.35))
#define KSCALE 32768.0f             // 16-bit fixed-point key scale (scores < 2.0)
#define INV_KSCALE (1.0f / 32768.0f)
#define BINW (32.0f / 32768.0f)     // key>>5 -> 2048 bins

typedef float nt4 __attribute__((ext_vector_type(4)));

__global__ __launch_bounds__(NTH, 4) void srp_kernel(
    const float* __restrict__ g_anchor,
    const float* __restrict__ g_lr,
    const float* __restrict__ g_pw,
    const float* __restrict__ g_bl,
    const float* __restrict__ g_mask,
    const float* __restrict__ g_sbud,
    const float* __restrict__ g_pbud,
    const float* __restrict__ g_psp,
    const float* __restrict__ g_ppa,
    const int*  __restrict__ g_front,
    float* __restrict__ g_out,
    int n_rows)
{
    constexpr float MIN_SPEECH = 1.0f;
    constexpr float MAX_EXPAND = 3.0f;
    constexpr float MIN_BW = 0.1f;
    constexpr float BIAS_W = 0.15f;
    constexpr float INV_TEMP = 1.0f / 0.12f;

    __shared__ unsigned s_cnt[NBIN];     // 8 KB: count histogram (all elements)
    __shared__ float    s_ws[NBIN];      // 8 KB: sum of m*tail^2*s per bin
    __shared__ float wred[NWAVE][5];
    __shared__ float s_scal[6];
    __shared__ float sh_thr;

    const int b = blockIdx.x;
    const int tid = threadIdx.x;
    const int wave = tid >> 6;
    const int lane = tid & 63;
    const long long row = (long long)b * T_DIM;
    const int f = g_front[b];
    const float sbud = g_sbud[b];        // uniform scalar loads, issued early
    const float pbud = g_pbud[b];

    // zero both histograms, then barrier BEFORE any global loads issue
    // (a later barrier would drain in-flight loads via vmcnt(0))
    #pragma unroll
    for (int i = 0; i < NBIN / NTH; ++i) {
        s_cnt[tid + NTH * i] = 0u;
        s_ws[tid + NTH * i]  = 0.f;
    }
    __syncthreads();                                                    // B0

    float SC1[16];   // pre? ps*m^2 : cand*tail*m   (speech)
    float P1[16];    // pp*m^2*pre                  (pause prefix part)
    float Mm[16];
    unsigned kp[8];  // 16 packed 16-bit keys
    float a_ps = 0.f, a_pp = 0.f, a_ts = 0.f, a_cs = 0.f, a_t2 = 0.f;

    // ---------- Pass 1: single read of all inputs; sums + keys + both hists ----------
    #pragma unroll
    for (int g = 0; g < GROUPS; ++g) {
        const int t0 = g * 2048 + (tid << 2);
        const float4 an4 = *reinterpret_cast<const float4*>(g_anchor + row + t0);
        const float4 lr4 = *reinterpret_cast<const float4*>(g_lr + row + t0);
        const float4 pw4 = *reinterpret_cast<const float4*>(g_pw + row + t0);
        const float4 bl4 = *reinterpret_cast<const float4*>(g_bl + row + t0);
        const float4 mk4 = *reinterpret_cast<const float4*>(g_mask + row + t0);
        const float4 ps4 = *reinterpret_cast<const float4*>(g_psp + row + t0);
        const float4 pp4 = *reinterpret_cast<const float4*>(g_ppa + row + t0);
        unsigned kk0 = 0u, kk1 = 0u;
        #pragma unroll
        for (int c = 0; c < 4; ++c) {
            const int i = (g << 2) + c;
            const int t = t0 + c;
            const float m   = (&mk4.x)[c];
            const float pre = (t < f) ? 1.0f : 0.0f;
            const float tl  = m * (1.0f - pre);
            const float ps = (&ps4.x)[c];
            const float pp = (&pp4.x)[c];
            a_ps += ps * m * pre;
            a_pp += pp * m * pre;
            a_ts += tl;
            a_t2 += tl * tl;
            const float an = fmaxf((&an4.x)[c], MIN_SPEECH);
            const float cand = fminf(fmaxf(an * __expf((&lr4.x)[c]), MIN_SPEECH),
                                     an * MAX_EXPAND) * m;
            a_cs += cand * tl;
            const float s = (fmaxf((&pw4.x)[c], 0.0f)
                             + BIAS_W * (MIN_BW + fmaxf((&bl4.x)[c], 0.0f))) * m;
            const unsigned key = (unsigned)fminf(s * KSCALE, 65535.0f);
            atomicAdd(&s_cnt[key >> 5], 1u);
            const float w = m * tl * tl * s;          // weight for denom term
            if (w > 0.0f) atomicAdd(&s_ws[key >> 5], w);
            if (c < 2) kk0 |= key << (16 * c);
            else       kk1 |= key << (16 * (c - 2));
            SC1[i] = ps * m * m * pre + cand * tl * m;
            P1[i]  = pp * m * m * pre;
            Mm[i]  = m;
        }
        kp[2 * g]     = kk0;
        kp[2 * g + 1] = kk1;
    }

    // wave-level reduce of the 5 accumulators
    #pragma unroll
    for (int o = 32; o > 0; o >>= 1) {
        a_ps += __shfl_down(a_ps, o, 64);
        a_pp += __shfl_down(a_pp, o, 64);
        a_ts += __shfl_down(a_ts, o, 64);
        a_cs += __shfl_down(a_cs, o, 64);
        a_t2 += __shfl_down(a_t2, o, 64);
    }
    if (lane == 0) {
        wred[wave][0] = a_ps; wred[wave][1] = a_pp;
        wred[wave][2] = a_ts; wred[wave][3] = a_cs;
        wred[wave][4] = a_t2;
    }
    __syncthreads();                                                    // B1

    // wave 1 (tid 64): row scalars; wave 0: histogram threshold scan — in parallel
    if (tid == 64) {
        float ps = 0.f, pp = 0.f, ts = 0.f, cs = 0.f, t2 = 0.f;
        for (int w = 0; w < NWAVE; ++w) {
            ps += wred[w][0]; pp += wred[w][1]; ts += wred[w][2];
            cs += wred[w][3]; t2 += wred[w][4];
        }
        const float sb = fmaxf(sbud, ps + ts * MIN_SPEECH);
        const float pb = fmaxf(pbud, pp);
        const float rem_s = sb - ps;
        const float cts = fmaxf(cs, 1e-6f);
        s_scal[0] = (ts > 0.0f && rem_s > 0.0f) ? (rem_s / cts) : 0.0f;  // scale_s
        s_scal[1] = fmaxf(pb - pp, 0.0f);                                // rem_p
        s_scal[2] = ts;
        s_scal[3] = 1e-6f / fmaxf(ts, 1.0f);                             // inv_ts6
        s_scal[5] = t2;                                                  // sum tail^2
    }
    if (wave == 0) {
        // lane l owns 32 descending bins: lane0 = topmost block
        const int base = NBIN - 32 * (lane + 1);
        unsigned csum = 0;
        #pragma unroll
        for (int i = 0; i < 32; ++i) csum += s_cnt[base + i];
        unsigned tot = csum;
        #pragma unroll
        for (int off = 1; off < 64; off <<= 1) {
            const unsigned n = __shfl_up(tot, off, 64);
            if (lane >= off) tot += n;
        }
        const unsigned excl = tot - csum;    // keys in bins strictly above this block
        if (excl < KEEP_K && excl + csum >= KEEP_K) {
            const unsigned need = KEEP_K - excl;
            unsigned c = 0;
            int bin = base;
            for (int i = 31; i >= 0; --i) {
                c += s_cnt[base + i];
                if (c >= need) { bin = base + i; break; }
            }
            sh_thr = (float)bin * BINW;
        }
    }
    __syncthreads();                                                    // B2

    const float thr = sh_thr;
    const float scale_s = s_scal[0];
    const float inv_ts6 = s_scal[3];

    // ---- early speech store: overlaps the denominator phase ----
    #pragma unroll
    for (int g = 0; g < GROUPS; ++g) {
        const int t0 = g * 2048 + (tid << 2);
        nt4 vs;
        #pragma unroll
        for (int c = 0; c < 4; ++c) {
            const int i = (g << 2) + c;
            const int t = t0 + c;
            vs[c] = (t < f) ? SC1[i] : SC1[i] * scale_s;
        }
        __builtin_nontemporal_store(vs, reinterpret_cast<nt4*>(g_out + row + t0));
    }

    // ---------- denominator from the weighted histogram (4 bins/thread) ----------
    float a_d = 0.0f;
    #pragma unroll
    for (int i = 0; i < NBIN / NTH; ++i) {
        const int bin = tid + NTH * i;               // stride-1 across lanes
        const float w = s_ws[bin];
        const float sc = ((float)bin + 0.5f) * BINW;
        a_d += w / (1.0f + __expf(-(sc - thr) * INV_TEMP));
    }
    #pragma unroll
    for (int o = 32; o > 0; o >>= 1) a_d += __shfl_down(a_d, o, 64);
    if (lane == 0) wred[wave][0] = a_d;
    __syncthreads();                                                    // B3
    if (tid == 0) {
        float d = 0.f;
        for (int w = 0; w < NWAVE; ++w) d += wred[w][0];
        d += s_scal[5] * inv_ts6;                    // fallback term: sum(tail^2)*1e-6/ts
        const float denom = fmaxf(d, 1e-6f);
        const float ts = s_scal[2];
        const float rem_p = s_scal[1];
        s_scal[4] = (ts > 0.0f && rem_p > 0.0f) ? (rem_p / denom) : 0.0f;  // scale_p
    }
    __syncthreads();                                                    // B4

    // ---------- pause compute (keys from registers) + store ----------
    const float scale_p = s_scal[4];
    const long long out_off = (long long)n_rows * T_DIM;
    #pragma unroll
    for (int g = 0; g < GROUPS; ++g) {
        const int t0 = g * 2048 + (tid << 2);
        const unsigned kk0 = kp[2 * g], kk1 = kp[2 * g + 1];
        const unsigned kk[4] = { kk0 & 0xFFFFu, kk0 >> 16, kk1 & 0xFFFFu, kk1 >> 16 };
        nt4 vp;
        #pragma unroll
        for (int c = 0; c < 4; ++c) {
            const int i = (g << 2) + c;
            const int t = t0 + c;
            const float m = Mm[i];
            const float pre = (t < f) ? 1.0f : 0.0f;
            const float tl = m * (1.0f - pre);
            const float s = (float)kk[c] * INV_KSCALE;
            const float gate = 1.0f / (1.0f + __expf(-(s - thr) * INV_TEMP));
            vp[c] = P1[i] + scale_p * tl * tl * (s * gate * m + inv_ts6);
        }
        __builtin_nontemporal_store(vp, reinterpret_cast<nt4*>(g_out + out_off + row + t0));
    }
}

extern "C" void kernel_launch(void* const* d_in, const int* in_sizes, int n_in,
                              void* d_out, int out_size, void* d_ws, size_t ws_size,
                              hipStream_t stream) {
    const float* anchor = (const float*)d_in[0];
    const float* lr     = (const float*)d_in[1];
    const float* pw     = (const float*)d_in[2];
    const float* bl     = (const float*)d_in[3];
    const float* mask   = (const float*)d_in[4];
    const float* sbud   = (const float*)d_in[5];
    const float* pbud   = (const float*)d_in[6];
    const float* psp    = (const float*)d_in[7];
    const float* ppa    = (const float*)d_in[8];
    const int*   front  = (const int*)d_in[9];
    float* out = (float*)d_out;
    const int B = in_sizes[5];   // speech_budget_win has B elements
    srp_kernel<<<B, NTH, 0, stream>>>(anchor, lr, pw, bl, mask, sbud, pbud,
                                      psp, ppa, front, out, B);
}

// Round 6
// 170.639 us; speedup vs baseline: 1.1378x; 1.1378x over previous
//
#include <hip/hip_runtime.h>

#define T_DIM 8192
#define NTH 512
#define NWAVE 8
#define GROUPS 4
#define NBIN 2048
#define KEEP_K 2867                 // max(1, round(8192 * 0.35))
#define KSCALE 32768.0f             // 16-bit fixed-point key scale (scores < 2.0)
#define INV_KSCALE (1.0f / 32768.0f)
#define BINW (32.0f / 32768.0f)     // key>>5 -> 2048 bins

typedef float nt4 __attribute__((ext_vector_type(4)));

__global__ __launch_bounds__(NTH, 2) void srp_kernel(
    const float* __restrict__ g_anchor,
    const float* __restrict__ g_lr,
    const float* __restrict__ g_pw,
    const float* __restrict__ g_bl,
    const float* __restrict__ g_mask,
    const float* __restrict__ g_sbud,
    const float* __restrict__ g_pbud,
    const float* __restrict__ g_psp,
    const float* __restrict__ g_ppa,
    const int*  __restrict__ g_front,
    float* __restrict__ g_out,
    int n_rows)
{
    constexpr float MIN_SPEECH = 1.0f;
    constexpr float MAX_EXPAND = 3.0f;
    constexpr float MIN_BW = 0.1f;
    constexpr float BIAS_W = 0.15f;
    constexpr float INV_TEMP = 1.0f / 0.12f;

    __shared__ unsigned s_cnt[NBIN];     // 8 KB: count histogram
    __shared__ float    s_ws[NBIN];      // 8 KB: sum of sigma*m*tail^2 per bin
    __shared__ float wred[NWAVE][5];
    __shared__ float s_scal[6];
    __shared__ float sh_thr;

    const int b = blockIdx.x;
    const int tid = threadIdx.x;
    const int wave = tid >> 6;
    const int lane = tid & 63;
    const long long row = (long long)b * T_DIM;
    const int f = g_front[b];
    const float sbud = g_sbud[b];
    const float pbud = g_pbud[b];

    #pragma unroll
    for (int i = 0; i < NBIN / NTH; ++i) {
        s_cnt[tid + NTH * i] = 0u;
        s_ws[tid + NTH * i]  = 0.f;
    }
    __syncthreads();                                                    // B0

    // per-thread state (kept small to avoid scratch spills):
    float SC1[16];   // pre? ps*m^2 : cand*tail*m            (speech)
    float PM[16];    // pre? pp*m^2 : m   (mutually exclusive; pause)
    unsigned kp[8];  // 16 packed 16-bit score keys
    float a_ps = 0.f, a_pp = 0.f, a_ts = 0.f, a_cs = 0.f, a_t2 = 0.f;

    // ---------- Pass 1: single read of all inputs; sums + keys + both hists ----------
    #pragma unroll
    for (int g = 0; g < GROUPS; ++g) {
        const int t0 = g * 2048 + (tid << 2);
        const float4 an4 = *reinterpret_cast<const float4*>(g_anchor + row + t0);
        const float4 lr4 = *reinterpret_cast<const float4*>(g_lr + row + t0);
        const float4 pw4 = *reinterpret_cast<const float4*>(g_pw + row + t0);
        const float4 bl4 = *reinterpret_cast<const float4*>(g_bl + row + t0);
        const float4 mk4 = *reinterpret_cast<const float4*>(g_mask + row + t0);
        const float4 ps4 = *reinterpret_cast<const float4*>(g_psp + row + t0);
        const float4 pp4 = *reinterpret_cast<const float4*>(g_ppa + row + t0);
        unsigned kk0 = 0u, kk1 = 0u;
        #pragma unroll
        for (int c = 0; c < 4; ++c) {
            const int i = (g << 2) + c;
            const int t = t0 + c;
            const float m   = (&mk4.x)[c];
            const float pre = (t < f) ? 1.0f : 0.0f;
            const float tl  = m * (1.0f - pre);
            const float ps = (&ps4.x)[c];
            const float pp = (&pp4.x)[c];
            a_ps += ps * m * pre;
            a_pp += pp * m * pre;
            a_ts += tl;
            a_t2 += tl * tl;
            const float an = fmaxf((&an4.x)[c], MIN_SPEECH);
            const float cand = fminf(fmaxf(an * __expf((&lr4.x)[c]), MIN_SPEECH),
                                     an * MAX_EXPAND) * m;
            a_cs += cand * tl;
            const float s = (fmaxf((&pw4.x)[c], 0.0f)
                             + BIAS_W * (MIN_BW + fmaxf((&bl4.x)[c], 0.0f))) * m;
            const unsigned key = (unsigned)fminf(s * KSCALE, 65535.0f);
            atomicAdd(&s_cnt[key >> 5], 1u);
            const float w = s * m * tl * tl;          // sigma*m*tail^2 (denom weight)
            if (w > 0.0f) atomicAdd(&s_ws[key >> 5], w);
            if (c < 2) kk0 |= key << (16 * c);
            else       kk1 |= key << (16 * (c - 2));
            SC1[i] = ps * m * m * pre + cand * tl * m;
            PM[i]  = (t < f) ? pp * m * m : m;
        }
        kp[2 * g]     = kk0;
        kp[2 * g + 1] = kk1;
    }

    #pragma unroll
    for (int o = 32; o > 0; o >>= 1) {
        a_ps += __shfl_down(a_ps, o, 64);
        a_pp += __shfl_down(a_pp, o, 64);
        a_ts += __shfl_down(a_ts, o, 64);
        a_cs += __shfl_down(a_cs, o, 64);
        a_t2 += __shfl_down(a_t2, o, 64);
    }
    if (lane == 0) {
        wred[wave][0] = a_ps; wred[wave][1] = a_pp;
        wred[wave][2] = a_ts; wred[wave][3] = a_cs;
        wred[wave][4] = a_t2;
    }
    __syncthreads();                                                    // B1

    // wave 1: row scalars; wave 0: histogram threshold scan — in parallel
    if (tid == 64) {
        float ps = 0.f, pp = 0.f, ts = 0.f, cs = 0.f, t2 = 0.f;
        for (int w = 0; w < NWAVE; ++w) {
            ps += wred[w][0]; pp += wred[w][1]; ts += wred[w][2];
            cs += wred[w][3]; t2 += wred[w][4];
        }
        const float sb = fmaxf(sbud, ps + ts * MIN_SPEECH);
        const float pb = fmaxf(pbud, pp);
        const float rem_s = sb - ps;
        const float cts = fmaxf(cs, 1e-6f);
        s_scal[0] = (ts > 0.0f && rem_s > 0.0f) ? (rem_s / cts) : 0.0f;  // scale_s
        s_scal[1] = fmaxf(pb - pp, 0.0f);                                // rem_p
        s_scal[2] = ts;
        s_scal[3] = 1e-6f / fmaxf(ts, 1.0f);                             // inv_ts6
        s_scal[5] = t2;                                                  // sum tail^2
    }
    if (wave == 0) {
        const int base = NBIN - 32 * (lane + 1);     // lane0 = topmost 32 bins
        unsigned csum = 0;
        #pragma unroll
        for (int i = 0; i < 32; ++i) csum += s_cnt[base + i];
        unsigned tot = csum;
        #pragma unroll
        for (int off = 1; off < 64; off <<= 1) {
            const unsigned n = __shfl_up(tot, off, 64);
            if (lane >= off) tot += n;
        }
        const unsigned excl = tot - csum;            // count strictly above this block
        if (excl < KEEP_K && excl + csum >= KEEP_K) {
            const unsigned need = KEEP_K - excl;
            unsigned c = 0;
            int bin = base;
            for (int i = 31; i >= 0; --i) {
                c += s_cnt[base + i];
                if (c >= need) { bin = base + i; break; }
            }
            sh_thr = (float)bin * BINW;
        }
    }
    __syncthreads();                                                    // B2

    const float thr = sh_thr;
    const float scale_s = s_scal[0];
    const float inv_ts6 = s_scal[3];

    // ---- early speech store: overlaps the denominator phase ----
    #pragma unroll
    for (int g = 0; g < GROUPS; ++g) {
        const int t0 = g * 2048 + (tid << 2);
        nt4 vs;
        #pragma unroll
        for (int c = 0; c < 4; ++c) {
            const int i = (g << 2) + c;
            const int t = t0 + c;
            vs[c] = (t < f) ? SC1[i] : SC1[i] * scale_s;
        }
        __builtin_nontemporal_store(vs, reinterpret_cast<nt4*>(g_out + row + t0));
    }

    // ---------- denominator from the weighted histogram (4 bins/thread) ----------
    float a_d = 0.0f;
    #pragma unroll
    for (int i = 0; i < NBIN / NTH; ++i) {
        const int bin = tid + NTH * i;
        const float w = s_ws[bin];
        const float sc = ((float)bin + 0.5f) * BINW;
        a_d += w / (1.0f + __expf(-(sc - thr) * INV_TEMP));
    }
    #pragma unroll
    for (int o = 32; o > 0; o >>= 1) a_d += __shfl_down(a_d, o, 64);
    if (lane == 0) wred[wave][0] = a_d;
    __syncthreads();                                                    // B3

    // every thread finishes the reduction itself (no extra barrier)
    float dsum = s_scal[5] * inv_ts6;                // fallback: sum(tail^2)*1e-6/ts
    #pragma unroll
    for (int w = 0; w < NWAVE; ++w) dsum += wred[w][0];
    const float denom = fmaxf(dsum, 1e-6f);
    const float scale_p = (s_scal[2] > 0.0f && s_scal[1] > 0.0f)
                          ? (s_scal[1] / denom) : 0.0f;

    // ---------- pause compute (keys + PM from registers) + store ----------
    const long long out_off = (long long)n_rows * T_DIM;
    #pragma unroll
    for (int g = 0; g < GROUPS; ++g) {
        const int t0 = g * 2048 + (tid << 2);
        const unsigned kk0 = kp[2 * g], kk1 = kp[2 * g + 1];
        const unsigned kk[4] = { kk0 & 0xFFFFu, kk0 >> 16, kk1 & 0xFFFFu, kk1 >> 16 };
        nt4 vp;
        #pragma unroll
        for (int c = 0; c < 4; ++c) {
            const int i = (g << 2) + c;
            const int t = t0 + c;
            const float pm = PM[i];                  // tail: m ; prefix: pp*m^2
            const float s = (float)kk[c] * INV_KSCALE;
            const float gate = 1.0f / (1.0f + __expf(-(s - thr) * INV_TEMP));
            // tail: scale_p * m * tail^2 * (sigma*gate*m + inv_ts6), tail = m
            const float tailv = scale_p * pm * pm * pm * (s * gate * pm + inv_ts6);
            vp[c] = (t < f) ? pm : tailv;
        }
        __builtin_nontemporal_store(vp, reinterpret_cast<nt4*>(g_out + out_off + row + t0));
    }
}

extern "C" void kernel_launch(void* const* d_in, const int* in_sizes, int n_in,
                              void* d_out, int out_size, void* d_ws, size_t ws_size,
                              hipStream_t stream) {
    const float* anchor = (const float*)d_in[0];
    const float* lr     = (const float*)d_in[1];
    const float* pw     = (const float*)d_in[2];
    const float* bl     = (const float*)d_in[3];
    const float* mask   = (const float*)d_in[4];
    const float* sbud   = (const float*)d_in[5];
    const float* pbud   = (const float*)d_in[6];
    const float* psp    = (const float*)d_in[7];
    const float* ppa    = (const float*)d_in[8];
    const int*   front  = (const int*)d_in[9];
    float* out = (float*)d_out;
    const int B = in_sizes[5];   // speech_budget_win has B elements
    srp_kernel<<<B, NTH, 0, stream>>>(anchor, lr, pw, bl, mask, sbud, pbud,
                                      psp, ppa, front, out, B);
}